// Round 1
// 76.342 us; speedup vs baseline: 1.0240x; 1.0240x over previous
//
#include <hip/hip_runtime.h>

#define NPTS   1024
#define HID    128
#define K_TAB  2048
#define U0f    (-10.0f)
#define U1f    (4.0f)

__device__ __forceinline__ float fast_exp2(float x) {
#if __has_builtin(__builtin_amdgcn_exp2f)
    return __builtin_amdgcn_exp2f(x);
#else
    return exp2f(x);
#endif
}
__device__ __forceinline__ float fast_rcp(float x) {
#if __has_builtin(__builtin_amdgcn_rcpf)
    return __builtin_amdgcn_rcpf(x);
#else
    return 1.0f / x;
#endif
}
__device__ __forceinline__ float fast_log2(float x) {
#if __has_builtin(__builtin_amdgcn_logf)
    return __builtin_amdgcn_logf(x);
#else
    return __log2f(x);
#endif
}
__device__ __forceinline__ float fast_rsq(float x) {
#if __has_builtin(__builtin_amdgcn_rsqf)
    return __builtin_amdgcn_rsqf(x);
#else
    return rsqrtf(x);
#endif
}
// tanh(x) = 1 - 2/(e^{2x}+1). Saturates correctly at +-inf.
__device__ __forceinline__ float fast_tanh(float x) {
    float e = fast_exp2(2.8853900817779268f * x);
    return 1.0f - 2.0f * fast_rcp(e + 1.0f);
}

// ---------------------------------------------------------------------------
// Kernel 1: mag(d) table, K_TAB+1 entries uniform in u = log2(d), d in
// [2^-10, 2^4].
// v2: 8 entries per block, 512 threads, grid (K_TAB/8)+1 = 257 blocks.
//   - W2 L2 traffic drops 65 MB -> 16.4 MB (each block streams W2 once,
//     each loaded element feeds 2 entries per thread + L1 reuse across the
//     4 hi2 groups).
//   - h1 stored k-major (h1t[k][entry]) so layer-2 inner loop is:
//     1 coalesced global load + 1 broadcast float2 LDS read + 2 FMA.
//   - FMA order per entry identical to v1 (k-ascending chain, same reduce
//     tree) -> bit-identical table.
// ---------------------------------------------------------------------------
__global__ __launch_bounds__(512) void build_table(const float* __restrict__ W1,
                                                   const float* __restrict__ b1,
                                                   const float* __restrict__ W2,
                                                   const float* __restrict__ b2,
                                                   const float* __restrict__ W3,
                                                   const float* __restrict__ b3,
                                                   float* __restrict__ tab)
{
    __shared__ __align__(16) float h1t[HID][8];   // [k][entry_local], 4 KB
    __shared__ __align__(16) float red[8][HID];   // 4 KB

    const int t = threadIdx.x, wave = t >> 6, lane = t & 63;
    const int hi2 = t >> 7;          // 0..3 (uniform within a wave)
    const int n   = t & 127;         // layer unit
    const float dU = (U1f - U0f) / (float)K_TAB;
    const int e0 = blockIdx.x * 8;

    // layer 1: two (entry, unit) tasks per thread; write transposed
#pragma unroll
    for (int q = 0; q < 2; ++q) {
        int el = hi2 + 4 * q;                    // 0..7 covered exactly once
        int e  = e0 + el; if (e > K_TAB) e = K_TAB;
        float u    = U0f + (float)e * dU;
        float d    = fast_exp2(u);
        float invc = fast_rcp(fmaxf(d, 0.01f));
        float inv2 = invc * invc;
        float z = fmaf(d, W1[n], fmaf(invc, W1[HID + n], fmaf(inv2, W1[2 * HID + n], b1[n])));
        h1t[n][el] = fast_tanh(z);
    }
    __syncthreads();

    // layer 2: thread (hi2, n) accumulates entries {2*hi2, 2*hi2+1}
    {
        const int p = hi2 * 2;
        float a0 = b2[n], a1 = b2[n];
#pragma unroll 16
        for (int k = 0; k < HID; ++k) {
            float  w = W2[k * HID + n];                       // coalesced, L1/L2-hot
            float2 h = *(const float2*)&h1t[k][p];            // broadcast read
            a0 = fmaf(h.x, w, a0);
            a1 = fmaf(h.y, w, a1);
        }
        float w3 = W3[n];
        red[p][n]     = fast_tanh(a0) * w3;
        red[p + 1][n] = fast_tanh(a1) * w3;
    }
    __syncthreads();

    // reduce 128 -> 1 per entry: wave w owns entry w (8 waves, 8 entries)
    {
        float s = red[wave][lane] + red[wave][lane + 64];
#pragma unroll
        for (int off = 1; off < 64; off <<= 1) s += __shfl_xor(s, off);
        if (lane == 0 && e0 + wave <= K_TAB) tab[e0 + wave] = s + b3[0];
    }
}

// ---------------------------------------------------------------------------
// Kernel 2: forces. 256 blocks per batch, 4 i's per block (1 per wave).
// Per pair: r^2, u = 0.5*log2(r^2) (no sqrt), table lerp, f += mag*diff*rsq.
// Self-pair contributes 0 (diff = 0). Each output written exactly once.
// v2: tab preload vectorized (float4), explicit 16B LDS alignment.
// ---------------------------------------------------------------------------
__global__ __launch_bounds__(256) void forces_kernel(const float* __restrict__ pos,
                                                     const float* __restrict__ tab,
                                                     float* __restrict__ out)
{
    __shared__ __align__(16) float tab_s[K_TAB + 4];   // 8.2 KB
    __shared__ __align__(16) float pos_s[NPTS * 3];    // 12 KB

    const int t = threadIdx.x, wave = t >> 6, lane = t & 63;
    const int b  = blockIdx.x >> 8;      // 256 blocks per batch
    const int ig = blockIdx.x & 255;

    {
        const float4* gt = (const float4*)tab;
        float4* st = (float4*)tab_s;
#pragma unroll
        for (int idx = t; idx < K_TAB / 4; idx += 256) st[idx] = gt[idx];  // 2 per thread
        if (t == 0) tab_s[K_TAB] = tab[K_TAB];                             // halo
    }
    {
        const float4* gp = (const float4*)(pos + b * NPTS * 3);
        float4* sp = (float4*)pos_s;
#pragma unroll
        for (int idx = t; idx < NPTS * 3 / 4; idx += 256) sp[idx] = gp[idx];
    }
    __syncthreads();

    const int   i  = ig * 4 + wave;
    const float px = pos_s[i * 3 + 0], py = pos_s[i * 3 + 1], pz = pos_s[i * 3 + 2];
    const float S  = (float)K_TAB / (U1f - U0f);

    float fx = 0.f, fy = 0.f, fz = 0.f;
#pragma unroll 4
    for (int j = lane; j < NPTS; j += 64) {
        float dx = px - pos_s[j * 3 + 0];
        float dy = py - pos_s[j * 3 + 1];
        float dz = pz - pos_s[j * 3 + 2];
        float r2 = fmaf(dx, dx, fmaf(dy, dy, dz * dz));
        float ta = fmaf(0.5f * fast_log2(r2), S, -U0f * S);   // r2=0 -> -inf -> k=0
        float kf = fminf(fmaxf(floorf(ta), 0.0f), (float)(K_TAB - 1));
        float fr = fminf(fmaxf(ta - kf, 0.0f), 1.0f);
        int   k  = (int)kf;
        float v0 = tab_s[k], v1 = tab_s[k + 1];
        float mag = fmaf(v1 - v0, fr, v0);
        float s   = mag * fminf(fast_rsq(r2), 100.0f);        // 1/max(d,0.01); rsq(0)=inf->100
        fx = fmaf(s, dx, fx);
        fy = fmaf(s, dy, fy);
        fz = fmaf(s, dz, fz);
    }
#pragma unroll
    for (int off = 1; off < 64; off <<= 1) {
        fx += __shfl_xor(fx, off);
        fy += __shfl_xor(fy, off);
        fz += __shfl_xor(fz, off);
    }
    if (lane == 0) {
        int o = (b * NPTS + i) * 3;
        out[o + 0] = fx;
        out[o + 1] = fy;
        out[o + 2] = fz;
    }
}

extern "C" void kernel_launch(void* const* d_in, const int* in_sizes, int n_in,
                              void* d_out, int out_size, void* d_ws, size_t ws_size,
                              hipStream_t stream) {
    const float* pos = (const float*)d_in[0];
    const float* W1  = (const float*)d_in[1];
    const float* b1  = (const float*)d_in[2];
    const float* W2  = (const float*)d_in[3];
    const float* b2  = (const float*)d_in[4];
    const float* W3  = (const float*)d_in[5];
    const float* b3  = (const float*)d_in[6];
    float* out = (float*)d_out;
    float* tab = (float*)d_ws;   // (K_TAB+1) floats

    int B = (in_sizes[0] / 3) / NPTS;
    build_table<<<K_TAB / 8 + 1, 512, 0, stream>>>(W1, b1, W2, b2, W3, b3, tab);
    forces_kernel<<<B * 256, 256, 0, stream>>>(pos, tab, out);
}